// Round 10
// baseline (816.165 us; speedup 1.0000x reference)
//
#include <hip/hip_runtime.h>

typedef __attribute__((ext_vector_type(8))) short short8v;   // 8 bf16
typedef __attribute__((ext_vector_type(4))) float f32x4;
typedef unsigned short u16;

__device__ inline u16 f2bf(float x){
  union{float f; unsigned u;} v; v.f = x;
  unsigned r = (v.u + 0x7FFFu + ((v.u >> 16) & 1u)) >> 16;
  return (u16)r;
}
__device__ inline float b2f(u16 u){
  union{unsigned u32; float f;} w; w.u32 = (unsigned)u << 16; return w.f;
}

// ---------------- preprocessing kernels ----------------

__global__ void k_deg(const int* __restrict__ col, int* __restrict__ indeg, int E){
  int e = blockIdx.x*blockDim.x + threadIdx.x;
  if (e < E) atomicAdd(&indeg[col[e]], 1);
}

__global__ void k_dinv(const int* __restrict__ indeg, float* __restrict__ dinv, int n){
  int i = blockIdx.x*blockDim.x + threadIdx.x;
  if (i < n) dinv[i] = rsqrtf((float)(indeg[i] + 1));
}

__global__ __launch_bounds__(256) void k_scan1(const int* __restrict__ indeg, int* __restrict__ rp,
                                               int* __restrict__ bsums, int n){
  __shared__ int s[256];
  int b = blockIdx.x, t = threadIdx.x;
  int base = b*1024 + t*4;
  int v[4]; int tsum = 0;
  #pragma unroll
  for (int j=0;j<4;j++){ v[j] = (base+j < n) ? indeg[base+j] : 0; tsum += v[j]; }
  s[t] = tsum; __syncthreads();
  for (int d=1; d<256; d<<=1){ int x = (t>=d) ? s[t-d] : 0; __syncthreads(); s[t] += x; __syncthreads(); }
  int run = s[t] - tsum;
  if (t == 255) bsums[b] = s[255];
  #pragma unroll
  for (int j=0;j<4;j++){ if (base+j < n){ rp[base+j] = run; } run += v[j]; }
}

__global__ __launch_bounds__(128) void k_scan2(int* bsums, int* rp, int nb, int n){
  __shared__ int s[128];
  int t = threadIdx.x;
  int orig = (t < nb) ? bsums[t] : 0;
  s[t] = orig; __syncthreads();
  for (int d=1; d<128; d<<=1){ int x = (t>=d) ? s[t-d] : 0; __syncthreads(); s[t] += x; __syncthreads(); }
  if (t < nb) bsums[t] = s[t] - orig;
  if (t == 127) rp[n] = s[127];
}

__global__ void k_scan3(int* __restrict__ rp, int* __restrict__ nxt, const int* __restrict__ bsums, int n){
  int i = blockIdx.x*blockDim.x + threadIdx.x;
  if (i < n){ int v = rp[i] + bsums[i >> 10]; rp[i] = v; nxt[i] = v; }
}

__global__ void k_scatter(const int* __restrict__ row, const int* __restrict__ col,
                          int* __restrict__ nxt, int* __restrict__ csr, int E){
  int e = blockIdx.x*blockDim.x + threadIdx.x;
  if (e < E){ int c = col[e]; int p = atomicAdd(&nxt[c], 1); csr[p] = row[e]; }
}

// x f32 [n][75] -> feature-major bf16 [10][n][8], zero-padded
__global__ void k_padfm(const float* __restrict__ x, u16* __restrict__ xfm, int n){
  long total = 10L*n;
  for (long idx = blockIdx.x*(long)blockDim.x + threadIdx.x; idx < total; idx += (long)gridDim.x*blockDim.x){
    int c8 = (int)(idx / n); int node = (int)(idx - (long)c8*n);
    short8v o;
    #pragma unroll
    for (int j=0;j<8;j++){
      int f = 8*c8 + j;
      o[j] = (short)f2bf(f < 75 ? x[(size_t)node*75 + f] : 0.f);
    }
    *(short8v*)&xfm[idx*8] = o;
  }
}

// W (f32, Kreal x NC) -> Wt (bf16, NCP x KPAD, transposed, zero-padded)
__global__ void k_wt(const float* __restrict__ W, u16* __restrict__ Wt,
                     int Kreal, int NC, int KPAD, int NCP){
  int idx = blockIdx.x*blockDim.x + threadIdx.x;
  if (idx >= NCP*KPAD) return;
  int c = idx / KPAD, k = idx % KPAD;
  float v = (c < NC && k < Kreal) ? W[(size_t)k*NC + c] : 0.0f;
  Wt[idx] = f2bf(v);
}

// ---------------- feature-major propagation: (node-block x chunk) parallel grid ----------------
// block = 256 threads = 256 nodes, ONE chunk (slab n*16B ~ 1.6MB, L2-fit).
// blockIdx.x = nb*NCHUNK + c8 -> chunk c8 maps to a subset of XCDs (reduces slab duplication).
// Edge list (src, dinv[src]) staged in LDS per block.

template<int NCHUNK>
__global__ __launch_bounds__(256) void k_prop_par(
    const u16* __restrict__ h, const float* __restrict__ dinv,
    const int* __restrict__ rp, const int* __restrict__ csr,
    u16* __restrict__ out, int n)
{
  constexpr int ECAP = 3200;   // mean 2048 edges / 256 nodes; Poisson tail ~25 sigma under cap
  __shared__ int   s_src[ECAP];
  __shared__ float s_w[ECAP];
  int tid = threadIdx.x;
  int nb = blockIdx.x / NCHUNK;
  int c8 = blockIdx.x - nb*NCHUNK;
  int nb0 = nb * 256;
  if (nb0 >= n) return;
  int nEnd = nb0 + 256; if (nEnd > n) nEnd = n;
  int e0b = rp[nb0];
  int ecnt = rp[nEnd] - e0b;
  int scnt = ecnt < ECAP ? ecnt : ECAP;
  for (int i = tid; i < scnt; i += 256){
    int s = csr[e0b + i];
    s_src[i] = s;
    s_w[i] = dinv[s];
  }
  __syncthreads();
  int node = nb0 + tid;
  if (node >= n) return;

  const u16* __restrict__ slab = h + (size_t)c8*n*8;
  float di = dinv[node];
  int l0 = rp[node] - e0b, l1 = rp[node+1] - e0b;
  int lcap = l1 < ECAP ? l1 : ECAP;

  float acc[8];
  {
    short8v v = *(const short8v*)&slab[(size_t)node*8];
    #pragma unroll
    for (int i=0;i<8;i++) acc[i] = di*b2f((u16)v[i]);
  }
  int e = l0;
  for (; e + 4 <= lcap; e += 4){
    int s0 = s_src[e], s1 = s_src[e+1], s2 = s_src[e+2], s3 = s_src[e+3];
    float w0 = s_w[e], w1 = s_w[e+1], w2 = s_w[e+2], w3 = s_w[e+3];
    short8v v0 = *(const short8v*)&slab[(size_t)s0*8];
    short8v v1 = *(const short8v*)&slab[(size_t)s1*8];
    short8v v2 = *(const short8v*)&slab[(size_t)s2*8];
    short8v v3 = *(const short8v*)&slab[(size_t)s3*8];
    #pragma unroll
    for (int i=0;i<8;i++)
      acc[i] += w0*b2f((u16)v0[i]) + w1*b2f((u16)v1[i]) + w2*b2f((u16)v2[i]) + w3*b2f((u16)v3[i]);
  }
  for (; e < lcap; ++e){
    int s = s_src[e]; float w = s_w[e];
    short8v v = *(const short8v*)&slab[(size_t)s*8];
    #pragma unroll
    for (int i=0;i<8;i++) acc[i] += w*b2f((u16)v[i]);
  }
  for (; e < l1; ++e){             // LDS-cap overflow fallback (never expected)
    int s = csr[e0b + e]; float w = dinv[s];
    short8v v = *(const short8v*)&slab[(size_t)s*8];
    #pragma unroll
    for (int i=0;i<8;i++) acc[i] += w*b2f((u16)v[i]);
  }
  short8v o;
  #pragma unroll
  for (int i=0;i<8;i++) o[i] = (short)f2bf(di*acc[i]);
  *(short8v*)&out[((size_t)c8*n + node)*8] = o;
}

// ---------------- bf16 MFMA GEMM, BM=64 column-loop, feature-major in/out ----------------

template<int KPAD, int FPIN, int POOL>
__global__ __launch_bounds__(256) void k_gemm_fm(
    const u16* __restrict__ Afm, const u16* __restrict__ Wt,
    const float* __restrict__ bias,
    u16* __restrict__ outfm, int NC, int FPOUT, int NT,
    const int* __restrict__ batch, unsigned* __restrict__ gpool, int ldg,
    int n, int G)
{
  constexpr int SA = KPAD + 8;
  constexpr int SW = KPAD + 8;
  constexpr int C8 = KPAD/8;
  constexpr int R8 = FPIN/8;
  __shared__ u16 As[64*SA];
  __shared__ u16 Ws[64*SW];
  __shared__ unsigned pmax[2][64];

  int tid = threadIdx.x;
  int r0 = blockIdx.x * 64;
  int w = tid >> 6, l = tid & 63;

  #pragma unroll
  for (int i = 0; i < 64*C8/256; ++i){
    int idx = tid + 256*i;
    int r = idx & 63, c8 = idx >> 6;
    short8v v = (short8v){0,0,0,0,0,0,0,0};
    if (c8 < R8 && r0 + r < n) v = *(const short8v*)&Afm[((size_t)c8*n + r0 + r)*8];
    *(short8v*)&As[r*SA + 8*c8] = v;
  }

  const u16* Ab = &As[(16*w + (l & 15))*SA + (l >> 4)*8];
  const u16* Bb = &Ws[(l & 15)*SW + (l >> 4)*8];

  for (int ct = 0; ct < NT; ++ct){
    if (ct) __syncthreads();
    #pragma unroll
    for (int i = 0; i < 64*C8/256; ++i){
      int idx = tid + 256*i;
      int wr = idx / C8, wk = idx % C8;
      *(short8v*)&Ws[wr*SW + 8*wk] = *(const short8v*)&Wt[(size_t)(ct*64 + wr)*KPAD + 8*wk];
    }
    if (POOL){ if (tid < 128) pmax[tid>>6][tid&63] = 0u; }
    __syncthreads();

    f32x4 acc[4];
    #pragma unroll
    for (int b=0;b<4;b++) acc[b] = (f32x4){0.f,0.f,0.f,0.f};

    #pragma unroll
    for (int ks = 0; ks < KPAD/32; ++ks){
      short8v a0 = *(const short8v*)(Ab + ks*32);
      short8v b0 = *(const short8v*)(Bb + ks*32);
      short8v b1 = *(const short8v*)(Bb + 16*SW + ks*32);
      short8v b2 = *(const short8v*)(Bb + 32*SW + ks*32);
      short8v b3 = *(const short8v*)(Bb + 48*SW + ks*32);
      acc[0] = __builtin_amdgcn_mfma_f32_16x16x32_bf16(a0, b0, acc[0], 0, 0, 0);
      acc[1] = __builtin_amdgcn_mfma_f32_16x16x32_bf16(a0, b1, acc[1], 0, 0, 0);
      acc[2] = __builtin_amdgcn_mfma_f32_16x16x32_bf16(a0, b2, acc[2], 0, 0, 0);
      acc[3] = __builtin_amdgcn_mfma_f32_16x16x32_bf16(a0, b3, acc[3], 0, 0, 0);
    }

    int rbase = r0 + 16*w + 4*(l >> 4);
    int cbase = ct*64;
    if (!POOL){
      #pragma unroll
      for (int cf=0;cf<4;cf++){
        int c = cbase + 16*cf + (l & 15);
        if (c >= FPOUT) continue;
        bool real = (c < NC);
        float bv = real ? bias[c] : 0.f;
        size_t obase = ((size_t)(c >> 3)*n)*8 + (c & 7);
        #pragma unroll
        for (int r=0;r<4;r++){
          int rr = rbase + r;
          if (rr < n){
            float v = real ? fmaxf(acc[cf][r] + bv, 0.f) : 0.f;
            outfm[obase + (size_t)rr*8] = f2bf(v);
          }
        }
      }
    } else {
      int g0 = batch[r0];
      #pragma unroll
      for (int cf=0;cf<4;cf++){
        int c = cbase + 16*cf + (l & 15);
        if (c >= NC) continue;
        float bv = bias[c];
        int curgi = -1; float m = 0.f;
        #pragma unroll
        for (int r=0;r<4;r++){
          int rr = rbase + r;
          if (rr < n){
            int gi = batch[rr] - g0; if (gi > 1) gi = 1;
            float v = fmaxf(acc[cf][r] + bv, 0.f);
            if (gi != curgi){
              if (curgi >= 0 && m > 0.f) atomicMax(&pmax[curgi][16*cf + (l&15)], __float_as_uint(m));
              curgi = gi; m = v;
            } else m = fmaxf(m, v);
          }
        }
        if (curgi >= 0 && m > 0.f) atomicMax(&pmax[curgi][16*cf + (l&15)], __float_as_uint(m));
      }
      __syncthreads();
      if (tid < 128){
        int gi = tid >> 6, cc = tid & 63;
        unsigned v = pmax[gi][cc];
        int gg = g0 + gi;
        if (v != 0u && (cbase + cc) < NC && gg < G)
          atomicMax(&gpool[(size_t)gg*ldg + (cbase + cc)], v);
      }
    }
  }
}

// ---------------- bf16 MFMA GEMM with BK=64 K-loop (head layers, f32 in/out) ----------------

__global__ __launch_bounds__(256) void k_gemm_kloop(
    const float* __restrict__ A, int lda, int Ktot,
    const u16* __restrict__ Wt, int ldw,
    const float* __restrict__ bias,
    float* __restrict__ out, int ldout, int NC,
    int n, int relu)
{
  constexpr int SA = 72, SW = 72;
  __shared__ u16 As[128*SA];
  __shared__ u16 Ws[64*SW];
  int tid = threadIdx.x;
  int r0 = blockIdx.x * 128, c0 = blockIdx.y * 64;
  int w = tid >> 6, l = tid & 63;

  f32x4 acc[2][4];
  #pragma unroll
  for (int a=0;a<2;a++)
    #pragma unroll
    for (int b=0;b<4;b++) acc[a][b] = (f32x4){0.f,0.f,0.f,0.f};

  const u16* Ab = &As[(32*w + (l & 15))*SA + (l >> 4)*8];
  const u16* Bb = &Ws[(l & 15)*SW + (l >> 4)*8];

  for (int k0 = 0; k0 < Ktot; k0 += 64){
    #pragma unroll
    for (int i=0;i<8;i++){
      int idx = tid + 256*i;
      int r = idx >> 4, c4 = idx & 15;
      float4 v = make_float4(0.f,0.f,0.f,0.f);
      if (r0 + r < n) v = *(const float4*)&A[(size_t)(r0+r)*lda + k0 + 4*c4];
      unsigned p01 = (unsigned)f2bf(v.x) | ((unsigned)f2bf(v.y) << 16);
      unsigned p23 = (unsigned)f2bf(v.z) | ((unsigned)f2bf(v.w) << 16);
      *(uint2*)&As[r*SA + 4*c4] = make_uint2(p01, p23);
    }
    #pragma unroll
    for (int i=0;i<2;i++){
      int idx = tid + 256*i;
      int wr = idx >> 3, wk = idx & 7;
      short8v wv = *(const short8v*)&Wt[(size_t)(c0+wr)*ldw + k0 + 8*wk];
      *(short8v*)&Ws[wr*SW + 8*wk] = wv;
    }
    __syncthreads();
    #pragma unroll
    for (int ks = 0; ks < 2; ++ks){
      short8v a0 = *(const short8v*)(Ab + ks*32);
      short8v a1 = *(const short8v*)(Ab + 16*SA + ks*32);
      short8v b0 = *(const short8v*)(Bb + ks*32);
      short8v b1 = *(const short8v*)(Bb + 16*SW + ks*32);
      short8v b2 = *(const short8v*)(Bb + 32*SW + ks*32);
      short8v b3 = *(const short8v*)(Bb + 48*SW + ks*32);
      acc[0][0] = __builtin_amdgcn_mfma_f32_16x16x32_bf16(a0, b0, acc[0][0], 0, 0, 0);
      acc[0][1] = __builtin_amdgcn_mfma_f32_16x16x32_bf16(a0, b1, acc[0][1], 0, 0, 0);
      acc[0][2] = __builtin_amdgcn_mfma_f32_16x16x32_bf16(a0, b2, acc[0][2], 0, 0, 0);
      acc[0][3] = __builtin_amdgcn_mfma_f32_16x16x32_bf16(a0, b3, acc[0][3], 0, 0, 0);
      acc[1][0] = __builtin_amdgcn_mfma_f32_16x16x32_bf16(a1, b0, acc[1][0], 0, 0, 0);
      acc[1][1] = __builtin_amdgcn_mfma_f32_16x16x32_bf16(a1, b1, acc[1][1], 0, 0, 0);
      acc[1][2] = __builtin_amdgcn_mfma_f32_16x16x32_bf16(a1, b2, acc[1][2], 0, 0, 0);
      acc[1][3] = __builtin_amdgcn_mfma_f32_16x16x32_bf16(a1, b3, acc[1][3], 0, 0, 0);
    }
    __syncthreads();
  }

  #pragma unroll
  for (int rf=0;rf<2;rf++){
    int rbase = r0 + 32*w + 16*rf + 4*(l >> 4);
    #pragma unroll
    for (int cf=0;cf<4;cf++){
      int c = c0 + 16*cf + (l & 15);
      if (c >= NC) continue;
      float bv = bias[c];
      #pragma unroll
      for (int r=0;r<4;r++){
        int rr = rbase + r;
        if (rr < n){
          float v = acc[rf][cf][r] + bv;
          if (relu) v = fmaxf(v, 0.f);
          out[(size_t)rr*ldout + c] = v;
        }
      }
    }
  }
}

// ---------------- launcher ----------------

extern "C" void kernel_launch(void* const* d_in, const int* in_sizes, int n_in,
                              void* d_out, int out_size, void* d_ws, size_t ws_size,
                              hipStream_t stream)
{
  const float* x   = (const float*)d_in[0];
  const int*   ei  = (const int*)d_in[1];
  const int*   batch = (const int*)d_in[2];
  const float* W1  = (const float*)d_in[3]; const float* b1  = (const float*)d_in[4];
  const float* W2  = (const float*)d_in[5]; const float* b2  = (const float*)d_in[6];
  const float* W3  = (const float*)d_in[7]; const float* b3  = (const float*)d_in[8];
  const float* Wg1 = (const float*)d_in[9]; const float* bg1 = (const float*)d_in[10];
  const float* Wg2 = (const float*)d_in[11]; const float* bg2 = (const float*)d_in[12];
  float* out = (float*)d_out;

  const int F1 = 75;
  int n = in_sizes[0] / F1;          // 100000
  int E = in_sizes[1] / 2;           // 800000
  int G = out_size / 128;            // 512
  const int* row = ei;
  const int* col = ei + E;

  char* ws = (char*)d_ws;
  size_t off = 0;
  auto alloc = [&](size_t bytes){ size_t o = off; off += (bytes + 255) & ~(size_t)255; return o; };
  u16*   xfm   = (u16*)  (ws + alloc((size_t)n*80*2));   // feature-major x; aliased as h1fm later
  u16*   qfm   = (u16*)  (ws + alloc((size_t)n*160*2));
  u16*   h2fm  = (u16*)  (ws + alloc((size_t)n*160*2));
  float* dinv  = (float*)(ws + alloc((size_t)n*4));
  int*   indeg = (int*)  (ws + alloc((size_t)n*4));
  int*   rp    = (int*)  (ws + alloc((size_t)(n+1)*4));
  int*   nxt   = (int*)  (ws + alloc((size_t)n*4));
  int*   csr   = (int*)  (ws + alloc((size_t)E*4));
  int*   bsums = (int*)  (ws + alloc(1024*4));
  unsigned* g  = (unsigned*)(ws + alloc((size_t)G*320*4));
  float* gh    = (float*)(ws + alloc((size_t)G*1024*4));
  u16* Wt1  = (u16*)(ws + alloc((size_t)128*96*2));
  u16* Wt2  = (u16*)(ws + alloc((size_t)192*96*2));
  u16* Wt3  = (u16*)(ws + alloc((size_t)320*160*2));
  u16* Wg1t = (u16*)(ws + alloc((size_t)1024*320*2));
  u16* Wg2t = (u16*)(ws + alloc((size_t)128*1024*2));
  u16* h1fm = xfm;   // alias: xfm dead after prop1

  hipMemsetAsync(indeg, 0, (size_t)n*4, stream);
  hipMemsetAsync(g, 0, (size_t)G*320*4, stream);

  k_deg<<<(E+255)/256, 256, 0, stream>>>(col, indeg, E);
  k_dinv<<<(n+255)/256, 256, 0, stream>>>(indeg, dinv, n);

  int nb = (n + 1023) / 1024;
  k_scan1<<<nb, 256, 0, stream>>>(indeg, rp, bsums, n);
  k_scan2<<<1, 128, 0, stream>>>(bsums, rp, nb, n);
  k_scan3<<<(n+255)/256, 256, 0, stream>>>(rp, nxt, bsums, n);
  k_scatter<<<(E+255)/256, 256, 0, stream>>>(row, col, nxt, csr, E);

  k_padfm<<<2048, 256, 0, stream>>>(x, xfm, n);
  k_wt<<<(128*96+255)/256, 256, 0, stream>>>(W1, Wt1, 75, 75, 96, 128);
  k_wt<<<(192*96+255)/256, 256, 0, stream>>>(W2, Wt2, 75, 150, 96, 192);
  k_wt<<<(320*160+255)/256, 256, 0, stream>>>(W3, Wt3, 150, 300, 160, 320);
  k_wt<<<(1024*320+255)/256, 256, 0, stream>>>(Wg1, Wg1t, 300, 1024, 320, 1024);
  k_wt<<<(128*1024+255)/256, 256, 0, stream>>>(Wg2, Wg2t, 1024, 128, 1024, 128);

  int nblk = (n + 255) / 256;   // 391
  int mb64 = (n + 63) / 64;     // 1563

  // layer 1: q = Ahat x ; h1 = relu(q@W1+b1)
  k_prop_par<10><<<nblk*10, 256, 0, stream>>>(xfm, dinv, rp, csr, qfm, n);
  k_gemm_fm<96,80,0><<<mb64, 256, 0, stream>>>(qfm, Wt1, b1, h1fm, 75, 80, 2,
                                               nullptr, nullptr, 0, n, G);
  // layer 2
  k_prop_par<10><<<nblk*10, 256, 0, stream>>>(h1fm, dinv, rp, csr, qfm, n);
  k_gemm_fm<96,80,0><<<mb64, 256, 0, stream>>>(qfm, Wt2, b2, h2fm, 150, 160, 3,
                                               nullptr, nullptr, 0, n, G);
  // layer 3 + fused relu + segment-max pool -> g (f32 bits, stride 320)
  k_prop_par<20><<<nblk*20, 256, 0, stream>>>(h2fm, dinv, rp, csr, qfm, n);
  k_gemm_fm<160,160,1><<<mb64, 256, 0, stream>>>(qfm, Wt3, b3, nullptr, 300, 320, 5,
                                                 batch, g, 320, n, G);
  // head 1: gh = relu(g @ Wg1 + bg1)
  {
    dim3 grid(G/128, 1024/64);
    k_gemm_kloop<<<grid, 256, 0, stream>>>((const float*)g, 320, 320, Wg1t, 320, bg1,
                                           gh, 1024, 1024, G, 1);
  }
  // head 2: out = gh @ Wg2 + bg2
  {
    dim3 grid(G/128, 128/64);
    k_gemm_kloop<<<grid, 256, 0, stream>>>(gh, 1024, 1024, Wg2t, 1024, bg2,
                                           out, 128, 128, G, 0);
  }
}

// Round 11
// 494.464 us; speedup vs baseline: 1.6506x; 1.6506x over previous
//
#include <hip/hip_runtime.h>

typedef __attribute__((ext_vector_type(8))) short short8v;   // 8 bf16
typedef __attribute__((ext_vector_type(4))) float f32x4;
typedef unsigned short u16;

__device__ inline u16 f2bf(float x){
  union{float f; unsigned u;} v; v.f = x;
  unsigned r = (v.u + 0x7FFFu + ((v.u >> 16) & 1u)) >> 16;
  return (u16)r;
}
__device__ inline float b2f(u16 u){
  union{unsigned u32; float f;} w; w.u32 = (unsigned)u << 16; return w.f;
}

// ---------------- preprocessing kernels ----------------

__global__ void k_deg(const int* __restrict__ col, int* __restrict__ indeg, int E){
  int e = blockIdx.x*blockDim.x + threadIdx.x;
  if (e < E) atomicAdd(&indeg[col[e]], 1);
}

__global__ void k_dinv(const int* __restrict__ indeg, float* __restrict__ dinv, int n){
  int i = blockIdx.x*blockDim.x + threadIdx.x;
  if (i < n) dinv[i] = rsqrtf((float)(indeg[i] + 1));
}

__global__ __launch_bounds__(256) void k_scan1(const int* __restrict__ indeg, int* __restrict__ rp,
                                               int* __restrict__ bsums, int n){
  __shared__ int s[256];
  int b = blockIdx.x, t = threadIdx.x;
  int base = b*1024 + t*4;
  int v[4]; int tsum = 0;
  #pragma unroll
  for (int j=0;j<4;j++){ v[j] = (base+j < n) ? indeg[base+j] : 0; tsum += v[j]; }
  s[t] = tsum; __syncthreads();
  for (int d=1; d<256; d<<=1){ int x = (t>=d) ? s[t-d] : 0; __syncthreads(); s[t] += x; __syncthreads(); }
  int run = s[t] - tsum;
  if (t == 255) bsums[b] = s[255];
  #pragma unroll
  for (int j=0;j<4;j++){ if (base+j < n){ rp[base+j] = run; } run += v[j]; }
}

__global__ __launch_bounds__(128) void k_scan2(int* bsums, int* rp, int nb, int n){
  __shared__ int s[128];
  int t = threadIdx.x;
  int orig = (t < nb) ? bsums[t] : 0;
  s[t] = orig; __syncthreads();
  for (int d=1; d<128; d<<=1){ int x = (t>=d) ? s[t-d] : 0; __syncthreads(); s[t] += x; __syncthreads(); }
  if (t < nb) bsums[t] = s[t] - orig;
  if (t == 127) rp[n] = s[127];
}

__global__ void k_scan3(int* __restrict__ rp, int* __restrict__ nxt, const int* __restrict__ bsums, int n){
  int i = blockIdx.x*blockDim.x + threadIdx.x;
  if (i < n){ int v = rp[i] + bsums[i >> 10]; rp[i] = v; nxt[i] = v; }
}

__global__ void k_scatter(const int* __restrict__ row, const int* __restrict__ col,
                          int* __restrict__ nxt, int* __restrict__ csr, int E){
  int e = blockIdx.x*blockDim.x + threadIdx.x;
  if (e < E){ int c = col[e]; int p = atomicAdd(&nxt[c], 1); csr[p] = row[e]; }
}

// x f32 [n][75] -> xb bf16 [n][80] zero-padded
__global__ void k_padb(const float* __restrict__ x, u16* __restrict__ xb, int n){
  long total = (long)n*80;
  for (long idx = blockIdx.x*(long)blockDim.x + threadIdx.x; idx < total; idx += (long)gridDim.x*blockDim.x){
    int r = (int)(idx/80), fcol = (int)(idx%80);
    xb[idx] = f2bf(fcol < 75 ? x[(size_t)r*75 + fcol] : 0.f);
  }
}

// W (f32, Kreal x NC) -> Wt (bf16, NCP x KPAD, transposed, zero-padded)
__global__ void k_wt(const float* __restrict__ W, u16* __restrict__ Wt,
                     int Kreal, int NC, int KPAD, int NCP){
  int idx = blockIdx.x*blockDim.x + threadIdx.x;
  if (idx >= NCP*KPAD) return;
  int c = idx / KPAD, k = idx % KPAD;
  float v = (c < NC && k < Kreal) ? W[(size_t)k*NC + c] : 0.0f;
  Wt[idx] = f2bf(v);
}

// ---------------- sparse propagation (bf16, node-major): out = D^-1/2 (A+I) D^-1/2 h ----------------
// thread = (node-slot, 8-feature chunk): every lane does one 16B gather per edge.

template<int FP>   // bf16 row width, multiple of 8
__global__ __launch_bounds__(256) void k_prop_bf(const u16* __restrict__ h, const float* __restrict__ dinv,
                                                 const int* __restrict__ rp, const int* __restrict__ csr,
                                                 u16* __restrict__ out, int n){
  constexpr int TPN = FP/8;
  constexpr int NPB = 256/TPN;
  int q = threadIdx.x / TPN;
  int t = threadIdx.x - q*TPN;
  if (q >= NPB) return;
  int node = blockIdx.x*NPB + q;
  if (node >= n) return;
  int f = 8*t;
  float di = dinv[node];
  float acc[8];
  {
    short8v v = *(const short8v*)&h[(size_t)node*FP + f];
    #pragma unroll
    for (int i=0;i<8;i++) acc[i] = di*b2f((u16)v[i]);
  }
  int e0 = rp[node], e1 = rp[node+1];
  int e = e0;
  for (; e + 4 <= e1; e += 4){
    int s0 = csr[e], s1 = csr[e+1], s2 = csr[e+2], s3 = csr[e+3];
    float d0 = dinv[s0], d1 = dinv[s1], d2 = dinv[s2], d3 = dinv[s3];
    short8v v0 = *(const short8v*)&h[(size_t)s0*FP + f];
    short8v v1 = *(const short8v*)&h[(size_t)s1*FP + f];
    short8v v2 = *(const short8v*)&h[(size_t)s2*FP + f];
    short8v v3 = *(const short8v*)&h[(size_t)s3*FP + f];
    #pragma unroll
    for (int i=0;i<8;i++)
      acc[i] += d0*b2f((u16)v0[i]) + d1*b2f((u16)v1[i]) + d2*b2f((u16)v2[i]) + d3*b2f((u16)v3[i]);
  }
  for (; e < e1; ++e){
    int s = csr[e]; float ds = dinv[s];
    short8v v = *(const short8v*)&h[(size_t)s*FP + f];
    #pragma unroll
    for (int i=0;i<8;i++) acc[i] += ds*b2f((u16)v[i]);
  }
  short8v o;
  #pragma unroll
  for (int i=0;i<8;i++) o[i] = (short)f2bf(di*acc[i]);
  *(short8v*)&out[(size_t)node*FP + f] = o;
}

// ---------------- bf16 MFMA GEMM, BM=64 column-loop (A staged ONCE): out = relu(A@W+b) ----------------
// 256 threads (4 waves); wave w owns rows 16w..16w+15; per col-tile 64 cols, acc[4] frags.

template<int KPAD, int LDA, int POOL>
__global__ __launch_bounds__(256) void k_gemm_bf(
    const u16* __restrict__ A, const u16* __restrict__ Wt,
    const float* __restrict__ bias,
    u16* __restrict__ out, int ldout, int NC, int NT,
    const int* __restrict__ batch, unsigned* __restrict__ gpool, int ldg,
    int n, int G)
{
  constexpr int SA = KPAD + 8;
  constexpr int SW = KPAD + 8;
  constexpr int C8 = KPAD/8;
  constexpr int R8 = LDA/8;
  __shared__ u16 As[64*SA];
  __shared__ u16 Ws[64*SW];
  __shared__ unsigned pmax[2][64];

  int tid = threadIdx.x;
  int r0 = blockIdx.x * 64;
  int w = tid >> 6, l = tid & 63;

  // stage A once: 64 x KPAD (bf16 direct, zero-fill beyond LDA)
  #pragma unroll
  for (int i = 0; i < 64*C8/256; ++i){
    int idx = tid + 256*i;
    int r = idx / C8, c8 = idx % C8;
    short8v v = (short8v){0,0,0,0,0,0,0,0};
    if (r0 + r < n && c8 < R8) v = *(const short8v*)&A[(size_t)(r0+r)*LDA + 8*c8];
    *(short8v*)&As[r*SA + 8*c8] = v;
  }

  const u16* Ab = &As[(16*w + (l & 15))*SA + (l >> 4)*8];
  const u16* Bb = &Ws[(l & 15)*SW + (l >> 4)*8];

  for (int ct = 0; ct < NT; ++ct){
    if (ct) __syncthreads();          // prior tile done reading Ws/pmax
    // stage W tile: 64 x KPAD
    #pragma unroll
    for (int i = 0; i < 64*C8/256; ++i){
      int idx = tid + 256*i;
      int wr = idx / C8, wk = idx % C8;
      *(short8v*)&Ws[wr*SW + 8*wk] = *(const short8v*)&Wt[(size_t)(ct*64 + wr)*KPAD + 8*wk];
    }
    if (POOL){ if (tid < 128) pmax[tid>>6][tid&63] = 0u; }
    __syncthreads();

    f32x4 acc[4];
    #pragma unroll
    for (int b=0;b<4;b++) acc[b] = (f32x4){0.f,0.f,0.f,0.f};

    #pragma unroll
    for (int ks = 0; ks < KPAD/32; ++ks){
      short8v a0 = *(const short8v*)(Ab + ks*32);
      short8v b0 = *(const short8v*)(Bb + ks*32);
      short8v b1 = *(const short8v*)(Bb + 16*SW + ks*32);
      short8v b2 = *(const short8v*)(Bb + 32*SW + ks*32);
      short8v b3 = *(const short8v*)(Bb + 48*SW + ks*32);
      acc[0] = __builtin_amdgcn_mfma_f32_16x16x32_bf16(a0, b0, acc[0], 0, 0, 0);
      acc[1] = __builtin_amdgcn_mfma_f32_16x16x32_bf16(a0, b1, acc[1], 0, 0, 0);
      acc[2] = __builtin_amdgcn_mfma_f32_16x16x32_bf16(a0, b2, acc[2], 0, 0, 0);
      acc[3] = __builtin_amdgcn_mfma_f32_16x16x32_bf16(a0, b3, acc[3], 0, 0, 0);
    }

    int rbase = r0 + 16*w + 4*(l >> 4);
    int cbase = ct*64;
    if (!POOL){
      #pragma unroll
      for (int cf=0;cf<4;cf++){
        int c = cbase + 16*cf + (l & 15);
        if (c >= ldout) continue;
        bool real = (c < NC);
        float bv = real ? bias[c] : 0.f;
        #pragma unroll
        for (int r=0;r<4;r++){
          int rr = rbase + r;
          if (rr < n){
            float v = real ? fmaxf(acc[cf][r] + bv, 0.f) : 0.f;
            out[(size_t)rr*ldout + c] = f2bf(v);
          }
        }
      }
    } else {
      int g0 = batch[r0];
      #pragma unroll
      for (int cf=0;cf<4;cf++){
        int c = cbase + 16*cf + (l & 15);
        if (c >= NC) continue;
        float bv = bias[c];
        int curgi = -1; float m = 0.f;
        #pragma unroll
        for (int r=0;r<4;r++){
          int rr = rbase + r;
          if (rr < n){
            int gi = batch[rr] - g0; if (gi > 1) gi = 1;
            float v = fmaxf(acc[cf][r] + bv, 0.f);
            if (gi != curgi){
              if (curgi >= 0 && m > 0.f) atomicMax(&pmax[curgi][16*cf + (l&15)], __float_as_uint(m));
              curgi = gi; m = v;
            } else m = fmaxf(m, v);
          }
        }
        if (curgi >= 0 && m > 0.f) atomicMax(&pmax[curgi][16*cf + (l&15)], __float_as_uint(m));
      }
      __syncthreads();
      if (tid < 128){
        int gi = tid >> 6, cc = tid & 63;
        unsigned v = pmax[gi][cc];
        int gg = g0 + gi;
        if (v != 0u && (cbase + cc) < NC && gg < G)
          atomicMax(&gpool[(size_t)gg*ldg + (cbase + cc)], v);
      }
    }
  }
}

// ---------------- bf16 MFMA GEMM with BK=64 K-loop (head layers, f32 in/out) ----------------

__global__ __launch_bounds__(256) void k_gemm_kloop(
    const float* __restrict__ A, int lda, int Ktot,
    const u16* __restrict__ Wt, int ldw,
    const float* __restrict__ bias,
    float* __restrict__ out, int ldout, int NC,
    int n, int relu)
{
  constexpr int SA = 72, SW = 72;
  __shared__ u16 As[128*SA];
  __shared__ u16 Ws[64*SW];
  int tid = threadIdx.x;
  int r0 = blockIdx.x * 128, c0 = blockIdx.y * 64;
  int w = tid >> 6, l = tid & 63;

  f32x4 acc[2][4];
  #pragma unroll
  for (int a=0;a<2;a++)
    #pragma unroll
    for (int b=0;b<4;b++) acc[a][b] = (f32x4){0.f,0.f,0.f,0.f};

  const u16* Ab = &As[(32*w + (l & 15))*SA + (l >> 4)*8];
  const u16* Bb = &Ws[(l & 15)*SW + (l >> 4)*8];

  for (int k0 = 0; k0 < Ktot; k0 += 64){
    #pragma unroll
    for (int i=0;i<8;i++){
      int idx = tid + 256*i;
      int r = idx >> 4, c4 = idx & 15;
      float4 v = make_float4(0.f,0.f,0.f,0.f);
      if (r0 + r < n) v = *(const float4*)&A[(size_t)(r0+r)*lda + k0 + 4*c4];
      unsigned p01 = (unsigned)f2bf(v.x) | ((unsigned)f2bf(v.y) << 16);
      unsigned p23 = (unsigned)f2bf(v.z) | ((unsigned)f2bf(v.w) << 16);
      *(uint2*)&As[r*SA + 4*c4] = make_uint2(p01, p23);
    }
    #pragma unroll
    for (int i=0;i<2;i++){
      int idx = tid + 256*i;
      int wr = idx >> 3, wk = idx & 7;
      short8v wv = *(const short8v*)&Wt[(size_t)(c0+wr)*ldw + k0 + 8*wk];
      *(short8v*)&Ws[wr*SW + 8*wk] = wv;
    }
    __syncthreads();
    #pragma unroll
    for (int ks = 0; ks < 2; ++ks){
      short8v a0 = *(const short8v*)(Ab + ks*32);
      short8v a1 = *(const short8v*)(Ab + 16*SA + ks*32);
      short8v b0 = *(const short8v*)(Bb + ks*32);
      short8v b1 = *(const short8v*)(Bb + 16*SW + ks*32);
      short8v b2 = *(const short8v*)(Bb + 32*SW + ks*32);
      short8v b3 = *(const short8v*)(Bb + 48*SW + ks*32);
      acc[0][0] = __builtin_amdgcn_mfma_f32_16x16x32_bf16(a0, b0, acc[0][0], 0, 0, 0);
      acc[0][1] = __builtin_amdgcn_mfma_f32_16x16x32_bf16(a0, b1, acc[0][1], 0, 0, 0);
      acc[0][2] = __builtin_amdgcn_mfma_f32_16x16x32_bf16(a0, b2, acc[0][2], 0, 0, 0);
      acc[0][3] = __builtin_amdgcn_mfma_f32_16x16x32_bf16(a0, b3, acc[0][3], 0, 0, 0);
      acc[1][0] = __builtin_amdgcn_mfma_f32_16x16x32_bf16(a1, b0, acc[1][0], 0, 0, 0);
      acc[1][1] = __builtin_amdgcn_mfma_f32_16x16x32_bf16(a1, b1, acc[1][1], 0, 0, 0);
      acc[1][2] = __builtin_amdgcn_mfma_f32_16x16x32_bf16(a1, b2, acc[1][2], 0, 0, 0);
      acc[1][3] = __builtin_amdgcn_mfma_f32_16x16x32_bf16(a1, b3, acc[1][3], 0, 0, 0);
    }
    __syncthreads();
  }

  #pragma unroll
  for (int rf=0;rf<2;rf++){
    int rbase = r0 + 32*w + 16*rf + 4*(l >> 4);
    #pragma unroll
    for (int cf=0;cf<4;cf++){
      int c = c0 + 16*cf + (l & 15);
      if (c >= NC) continue;
      float bv = bias[c];
      #pragma unroll
      for (int r=0;r<4;r++){
        int rr = rbase + r;
        if (rr < n){
          float v = acc[rf][cf][r] + bv;
          if (relu) v = fmaxf(v, 0.f);
          out[(size_t)rr*ldout + c] = v;
        }
      }
    }
  }
}

// ---------------- launcher ----------------

extern "C" void kernel_launch(void* const* d_in, const int* in_sizes, int n_in,
                              void* d_out, int out_size, void* d_ws, size_t ws_size,
                              hipStream_t stream)
{
  const float* x   = (const float*)d_in[0];
  const int*   ei  = (const int*)d_in[1];
  const int*   batch = (const int*)d_in[2];
  const float* W1  = (const float*)d_in[3]; const float* b1  = (const float*)d_in[4];
  const float* W2  = (const float*)d_in[5]; const float* b2  = (const float*)d_in[6];
  const float* W3  = (const float*)d_in[7]; const float* b3  = (const float*)d_in[8];
  const float* Wg1 = (const float*)d_in[9]; const float* bg1 = (const float*)d_in[10];
  const float* Wg2 = (const float*)d_in[11]; const float* bg2 = (const float*)d_in[12];
  float* out = (float*)d_out;

  const int F1 = 75;
  int n = in_sizes[0] / F1;          // 100000
  int E = in_sizes[1] / 2;           // 800000
  int G = out_size / 128;            // 512
  const int* row = ei;
  const int* col = ei + E;

  char* ws = (char*)d_ws;
  size_t off = 0;
  auto alloc = [&](size_t bytes){ size_t o = off; off += (bytes + 255) & ~(size_t)255; return o; };
  u16*   xb    = (u16*)  (ws + alloc((size_t)n*80*2));   // padded bf16 x; aliased as h1 later
  u16*   qb    = (u16*)  (ws + alloc((size_t)n*160*2));  // propagated features (stride 80 or 160)
  u16*   h2b   = (u16*)  (ws + alloc((size_t)n*160*2));
  float* dinv  = (float*)(ws + alloc((size_t)n*4));
  int*   indeg = (int*)  (ws + alloc((size_t)n*4));
  int*   rp    = (int*)  (ws + alloc((size_t)(n+1)*4));
  int*   nxt   = (int*)  (ws + alloc((size_t)n*4));
  int*   csr   = (int*)  (ws + alloc((size_t)E*4));
  int*   bsums = (int*)  (ws + alloc(1024*4));
  unsigned* g  = (unsigned*)(ws + alloc((size_t)G*320*4));
  float* gh    = (float*)(ws + alloc((size_t)G*1024*4));
  u16* Wt1  = (u16*)(ws + alloc((size_t)128*96*2));
  u16* Wt2  = (u16*)(ws + alloc((size_t)192*96*2));
  u16* Wt3  = (u16*)(ws + alloc((size_t)320*160*2));
  u16* Wg1t = (u16*)(ws + alloc((size_t)1024*320*2));
  u16* Wg2t = (u16*)(ws + alloc((size_t)128*1024*2));
  u16* h1b = xb;   // alias: xb dead after prop1

  hipMemsetAsync(indeg, 0, (size_t)n*4, stream);
  hipMemsetAsync(g, 0, (size_t)G*320*4, stream);

  k_deg<<<(E+255)/256, 256, 0, stream>>>(col, indeg, E);
  k_dinv<<<(n+255)/256, 256, 0, stream>>>(indeg, dinv, n);

  int nb = (n + 1023) / 1024;
  k_scan1<<<nb, 256, 0, stream>>>(indeg, rp, bsums, n);
  k_scan2<<<1, 128, 0, stream>>>(bsums, rp, nb, n);
  k_scan3<<<(n+255)/256, 256, 0, stream>>>(rp, nxt, bsums, n);
  k_scatter<<<(E+255)/256, 256, 0, stream>>>(row, col, nxt, csr, E);

  k_padb<<<4096, 256, 0, stream>>>(x, xb, n);
  k_wt<<<(128*96+255)/256, 256, 0, stream>>>(W1, Wt1, 75, 75, 96, 128);
  k_wt<<<(192*96+255)/256, 256, 0, stream>>>(W2, Wt2, 75, 150, 96, 192);
  k_wt<<<(320*160+255)/256, 256, 0, stream>>>(W3, Wt3, 150, 300, 160, 320);
  k_wt<<<(1024*320+255)/256, 256, 0, stream>>>(Wg1, Wg1t, 300, 1024, 320, 1024);
  k_wt<<<(128*1024+255)/256, 256, 0, stream>>>(Wg2, Wg2t, 1024, 128, 1024, 128);

  int mb64 = (n + 63) / 64;     // 1563

  // layer 1: q = Ahat xb ; h1 = relu(q@W1+b1)
  k_prop_bf<80><<<(n+24)/25, 256, 0, stream>>>(xb, dinv, rp, csr, qb, n);
  k_gemm_bf<96,80,0><<<mb64, 256, 0, stream>>>(qb, Wt1, b1, h1b, 80, 75, 2,
                                               nullptr, nullptr, 0, n, G);
  // layer 2
  k_prop_bf<80><<<(n+24)/25, 256, 0, stream>>>(h1b, dinv, rp, csr, qb, n);
  k_gemm_bf<96,80,0><<<mb64, 256, 0, stream>>>(qb, Wt2, b2, h2b, 160, 150, 3,
                                               nullptr, nullptr, 0, n, G);
  // layer 3 + fused relu + segment-max pool -> g (f32 bits, stride 320)
  k_prop_bf<160><<<(n+11)/12, 256, 0, stream>>>(h2b, dinv, rp, csr, qb, n);
  k_gemm_bf<160,160,1><<<mb64, 256, 0, stream>>>(qb, Wt3, b3, nullptr, 0, 300, 5,
                                                 batch, g, 320, n, G);
  // head 1: gh = relu(g @ Wg1 + bg1)
  {
    dim3 grid(G/128, 1024/64);
    k_gemm_kloop<<<grid, 256, 0, stream>>>((const float*)g, 320, 320, Wg1t, 320, bg1,
                                           gh, 1024, 1024, G, 1);
  }
  // head 2: out = gh @ Wg2 + bg2
  {
    dim3 grid(G/128, 128/64);
    k_gemm_kloop<<<grid, 256, 0, stream>>>(gh, 1024, 1024, Wg2t, 1024, bg2,
                                           out, 128, 128, G, 0);
  }
}

// Round 12
// 434.871 us; speedup vs baseline: 1.8768x; 1.1370x over previous
//
#include <hip/hip_runtime.h>

typedef __attribute__((ext_vector_type(8))) short short8v;   // 8 bf16
typedef __attribute__((ext_vector_type(4))) float f32x4;
typedef unsigned short u16;

__device__ inline u16 f2bf(float x){
  union{float f; unsigned u;} v; v.f = x;
  unsigned r = (v.u + 0x7FFFu + ((v.u >> 16) & 1u)) >> 16;
  return (u16)r;
}
__device__ inline float b2f(u16 u){
  union{unsigned u32; float f;} w; w.u32 = (unsigned)u << 16; return w.f;
}

// ---------------- preprocessing kernels ----------------

__global__ void k_deg(const int* __restrict__ col, int* __restrict__ indeg, int E){
  int e = blockIdx.x*blockDim.x + threadIdx.x;
  if (e < E) atomicAdd(&indeg[col[e]], 1);
}

__global__ void k_dinv(const int* __restrict__ indeg, float* __restrict__ dinv, int n){
  int i = blockIdx.x*blockDim.x + threadIdx.x;
  if (i < n) dinv[i] = rsqrtf((float)(indeg[i] + 1));
}

__global__ __launch_bounds__(256) void k_scan1(const int* __restrict__ indeg, int* __restrict__ rp,
                                               int* __restrict__ bsums, int n){
  __shared__ int s[256];
  int b = blockIdx.x, t = threadIdx.x;
  int base = b*1024 + t*4;
  int v[4]; int tsum = 0;
  #pragma unroll
  for (int j=0;j<4;j++){ v[j] = (base+j < n) ? indeg[base+j] : 0; tsum += v[j]; }
  s[t] = tsum; __syncthreads();
  for (int d=1; d<256; d<<=1){ int x = (t>=d) ? s[t-d] : 0; __syncthreads(); s[t] += x; __syncthreads(); }
  int run = s[t] - tsum;
  if (t == 255) bsums[b] = s[255];
  #pragma unroll
  for (int j=0;j<4;j++){ if (base+j < n){ rp[base+j] = run; } run += v[j]; }
}

__global__ __launch_bounds__(128) void k_scan2(int* bsums, int* rp, int nb, int n){
  __shared__ int s[128];
  int t = threadIdx.x;
  int orig = (t < nb) ? bsums[t] : 0;
  s[t] = orig; __syncthreads();
  for (int d=1; d<128; d<<=1){ int x = (t>=d) ? s[t-d] : 0; __syncthreads(); s[t] += x; __syncthreads(); }
  if (t < nb) bsums[t] = s[t] - orig;
  if (t == 127) rp[n] = s[127];
}

__global__ void k_scan3(int* __restrict__ rp, int* __restrict__ nxt, const int* __restrict__ bsums, int n){
  int i = blockIdx.x*blockDim.x + threadIdx.x;
  if (i < n){ int v = rp[i] + bsums[i >> 10]; rp[i] = v; nxt[i] = v; }
}

__global__ void k_scatter(const int* __restrict__ row, const int* __restrict__ col,
                          int* __restrict__ nxt, int* __restrict__ csr, int E){
  int e = blockIdx.x*blockDim.x + threadIdx.x;
  if (e < E){ int c = col[e]; int p = atomicAdd(&nxt[c], 1); csr[p] = row[e]; }
}

// x f32 [n][75] -> xb bf16 [n][80] zero-padded
__global__ void k_padb(const float* __restrict__ x, u16* __restrict__ xb, int n){
  long total = (long)n*80;
  for (long idx = blockIdx.x*(long)blockDim.x + threadIdx.x; idx < total; idx += (long)gridDim.x*blockDim.x){
    int r = (int)(idx/80), fcol = (int)(idx%80);
    xb[idx] = f2bf(fcol < 75 ? x[(size_t)r*75 + fcol] : 0.f);
  }
}

// W (f32, Kreal x NC) -> Wt (bf16, NCP x KPAD, transposed, zero-padded)
__global__ void k_wt(const float* __restrict__ W, u16* __restrict__ Wt,
                     int Kreal, int NC, int KPAD, int NCP){
  int idx = blockIdx.x*blockDim.x + threadIdx.x;
  if (idx >= NCP*KPAD) return;
  int c = idx / KPAD, k = idx % KPAD;
  float v = (c < NC && k < Kreal) ? W[(size_t)k*NC + c] : 0.0f;
  Wt[idx] = f2bf(v);
}

// ---------------- sparse propagation (bf16, node-major): out = D^-1/2 (A+I) D^-1/2 h ----------------

template<int FP>   // bf16 row width, multiple of 8
__global__ __launch_bounds__(256) void k_prop_bf(const u16* __restrict__ h, const float* __restrict__ dinv,
                                                 const int* __restrict__ rp, const int* __restrict__ csr,
                                                 u16* __restrict__ out, int n){
  constexpr int TPN = FP/8;
  constexpr int NPB = 256/TPN;
  int q = threadIdx.x / TPN;
  int t = threadIdx.x - q*TPN;
  if (q >= NPB) return;
  int node = blockIdx.x*NPB + q;
  if (node >= n) return;
  int f = 8*t;
  float di = dinv[node];
  float acc[8];
  {
    short8v v = *(const short8v*)&h[(size_t)node*FP + f];
    #pragma unroll
    for (int i=0;i<8;i++) acc[i] = di*b2f((u16)v[i]);
  }
  int e0 = rp[node], e1 = rp[node+1];
  int e = e0;
  for (; e + 4 <= e1; e += 4){
    int s0 = csr[e], s1 = csr[e+1], s2 = csr[e+2], s3 = csr[e+3];
    float d0 = dinv[s0], d1 = dinv[s1], d2 = dinv[s2], d3 = dinv[s3];
    short8v v0 = *(const short8v*)&h[(size_t)s0*FP + f];
    short8v v1 = *(const short8v*)&h[(size_t)s1*FP + f];
    short8v v2 = *(const short8v*)&h[(size_t)s2*FP + f];
    short8v v3 = *(const short8v*)&h[(size_t)s3*FP + f];
    #pragma unroll
    for (int i=0;i<8;i++)
      acc[i] += d0*b2f((u16)v0[i]) + d1*b2f((u16)v1[i]) + d2*b2f((u16)v2[i]) + d3*b2f((u16)v3[i]);
  }
  for (; e < e1; ++e){
    int s = csr[e]; float ds = dinv[s];
    short8v v = *(const short8v*)&h[(size_t)s*FP + f];
    #pragma unroll
    for (int i=0;i<8;i++) acc[i] += ds*b2f((u16)v[i]);
  }
  short8v o;
  #pragma unroll
  for (int i=0;i<8;i++) o[i] = (short)f2bf(di*acc[i]);
  *(short8v*)&out[(size_t)node*FP + f] = o;
}

// ---------------- bf16 MFMA GEMM, BM=64 column-loop, W reg-double-buffered ----------------
// 256 threads (4 waves); A staged once; W tile ct+1 prefetched into regs during tile ct's MFMA.

template<int KPAD, int LDA, int POOL>
__global__ __launch_bounds__(256) void k_gemm_bf(
    const u16* __restrict__ A, const u16* __restrict__ Wt,
    const float* __restrict__ bias,
    u16* __restrict__ out, int ldout, int NC, int NT,
    const int* __restrict__ batch, unsigned* __restrict__ gpool, int ldg,
    int n, int G)
{
  constexpr int SA = KPAD + 8;
  constexpr int SW = KPAD + 8;
  constexpr int C8 = KPAD/8;
  constexpr int R8 = LDA/8;
  constexpr int WL = 64*C8/256;   // W-stage loads per thread
  __shared__ u16 As[64*SA];
  __shared__ u16 Ws[64*SW];
  __shared__ unsigned pmax[2][64];

  int tid = threadIdx.x;
  int r0 = blockIdx.x * 64;
  int w = tid >> 6, l = tid & 63;

  // stage A once: 64 x KPAD (bf16 direct, zero-fill beyond LDA)
  #pragma unroll
  for (int i = 0; i < 64*C8/256; ++i){
    int idx = tid + 256*i;
    int r = idx / C8, c8 = idx % C8;
    short8v v = (short8v){0,0,0,0,0,0,0,0};
    if (r0 + r < n && c8 < R8) v = *(const short8v*)&A[(size_t)(r0+r)*LDA + 8*c8];
    *(short8v*)&As[r*SA + 8*c8] = v;
  }

  // prefetch W tile 0 into regs
  short8v wreg[WL];
  #pragma unroll
  for (int i = 0; i < WL; ++i){
    int idx = tid + 256*i;
    int wr = idx / C8, wk = idx % C8;
    wreg[i] = *(const short8v*)&Wt[(size_t)wr*KPAD + 8*wk];
  }

  const u16* Ab = &As[(16*w + (l & 15))*SA + (l >> 4)*8];
  const u16* Bb = &Ws[(l & 15)*SW + (l >> 4)*8];

  for (int ct = 0; ct < NT; ++ct){
    __syncthreads();                  // prior tile done reading Ws (and A-stage visible on ct==0)
    #pragma unroll
    for (int i = 0; i < WL; ++i){
      int idx = tid + 256*i;
      int wr = idx / C8, wk = idx % C8;
      *(short8v*)&Ws[wr*SW + 8*wk] = wreg[i];
    }
    if (POOL){ if (tid < 128) pmax[tid>>6][tid&63] = 0u; }
    __syncthreads();                  // Ws visible

    if (ct + 1 < NT){                 // issue next tile's loads; latency hides under MFMA
      #pragma unroll
      for (int i = 0; i < WL; ++i){
        int idx = tid + 256*i;
        int wr = idx / C8, wk = idx % C8;
        wreg[i] = *(const short8v*)&Wt[(size_t)((ct+1)*64 + wr)*KPAD + 8*wk];
      }
    }

    f32x4 acc[4];
    #pragma unroll
    for (int b=0;b<4;b++) acc[b] = (f32x4){0.f,0.f,0.f,0.f};

    #pragma unroll
    for (int ks = 0; ks < KPAD/32; ++ks){
      short8v a0 = *(const short8v*)(Ab + ks*32);
      short8v b0 = *(const short8v*)(Bb + ks*32);
      short8v b1 = *(const short8v*)(Bb + 16*SW + ks*32);
      short8v b2 = *(const short8v*)(Bb + 32*SW + ks*32);
      short8v b3 = *(const short8v*)(Bb + 48*SW + ks*32);
      acc[0] = __builtin_amdgcn_mfma_f32_16x16x32_bf16(a0, b0, acc[0], 0, 0, 0);
      acc[1] = __builtin_amdgcn_mfma_f32_16x16x32_bf16(a0, b1, acc[1], 0, 0, 0);
      acc[2] = __builtin_amdgcn_mfma_f32_16x16x32_bf16(a0, b2, acc[2], 0, 0, 0);
      acc[3] = __builtin_amdgcn_mfma_f32_16x16x32_bf16(a0, b3, acc[3], 0, 0, 0);
    }

    int rbase = r0 + 16*w + 4*(l >> 4);
    int cbase = ct*64;
    if (!POOL){
      #pragma unroll
      for (int cf=0;cf<4;cf++){
        int c = cbase + 16*cf + (l & 15);
        if (c >= ldout) continue;
        bool real = (c < NC);
        float bv = real ? bias[c] : 0.f;
        #pragma unroll
        for (int r=0;r<4;r++){
          int rr = rbase + r;
          if (rr < n){
            float v = real ? fmaxf(acc[cf][r] + bv, 0.f) : 0.f;
            out[(size_t)rr*ldout + c] = f2bf(v);
          }
        }
      }
    } else {
      int g0 = batch[r0];
      #pragma unroll
      for (int cf=0;cf<4;cf++){
        int c = cbase + 16*cf + (l & 15);
        if (c >= NC) continue;
        float bv = bias[c];
        int curgi = -1; float m = 0.f;
        #pragma unroll
        for (int r=0;r<4;r++){
          int rr = rbase + r;
          if (rr < n){
            int gi = batch[rr] - g0; if (gi > 1) gi = 1;
            float v = fmaxf(acc[cf][r] + bv, 0.f);
            if (gi != curgi){
              if (curgi >= 0 && m > 0.f) atomicMax(&pmax[curgi][16*cf + (l&15)], __float_as_uint(m));
              curgi = gi; m = v;
            } else m = fmaxf(m, v);
          }
        }
        if (curgi >= 0 && m > 0.f) atomicMax(&pmax[curgi][16*cf + (l&15)], __float_as_uint(m));
      }
      __syncthreads();
      if (tid < 128){
        int gi = tid >> 6, cc = tid & 63;
        unsigned v = pmax[gi][cc];
        int gg = g0 + gi;
        if (v != 0u && (cbase + cc) < NC && gg < G)
          atomicMax(&gpool[(size_t)gg*ldg + (cbase + cc)], v);
      }
    }
  }
}

// ---------------- head GEMM, K-split: one BK=64 chunk per block -> f32 partials ----------------
// grid (rowblocks of 128, coltiles of 64, kchunks). A f32 [rows][lda]; Wt bf16 [NCP][ldw].

__global__ __launch_bounds__(256) void k_gemm_kc(
    const float* __restrict__ A, int lda,
    const u16* __restrict__ Wt, int ldw,
    float* __restrict__ P, int ldp,
    int rows, int NC)
{
  constexpr int SA = 72, SW = 72;
  __shared__ u16 As[128*SA];
  __shared__ u16 Ws[64*SW];
  int tid = threadIdx.x;
  int r0 = blockIdx.x * 128, c0 = blockIdx.y * 64, k0 = blockIdx.z * 64;
  int w = tid >> 6, l = tid & 63;

  #pragma unroll
  for (int i=0;i<8;i++){
    int idx = tid + 256*i;
    int r = idx >> 4, c4 = idx & 15;
    float4 v = make_float4(0.f,0.f,0.f,0.f);
    if (r0 + r < rows) v = *(const float4*)&A[(size_t)(r0+r)*lda + k0 + 4*c4];
    unsigned p01 = (unsigned)f2bf(v.x) | ((unsigned)f2bf(v.y) << 16);
    unsigned p23 = (unsigned)f2bf(v.z) | ((unsigned)f2bf(v.w) << 16);
    *(uint2*)&As[r*SA + 4*c4] = make_uint2(p01, p23);
  }
  #pragma unroll
  for (int i=0;i<2;i++){
    int idx = tid + 256*i;
    int wr = idx >> 3, wk = idx & 7;
    *(short8v*)&Ws[wr*SW + 8*wk] = *(const short8v*)&Wt[(size_t)(c0+wr)*ldw + k0 + 8*wk];
  }
  __syncthreads();

  const u16* Ab = &As[(32*w + (l & 15))*SA + (l >> 4)*8];
  const u16* Bb = &Ws[(l & 15)*SW + (l >> 4)*8];

  f32x4 acc[2][4];
  #pragma unroll
  for (int a=0;a<2;a++)
    #pragma unroll
    for (int b=0;b<4;b++) acc[a][b] = (f32x4){0.f,0.f,0.f,0.f};

  #pragma unroll
  for (int ks = 0; ks < 2; ++ks){
    short8v a0 = *(const short8v*)(Ab + ks*32);
    short8v a1 = *(const short8v*)(Ab + 16*SA + ks*32);
    short8v b0 = *(const short8v*)(Bb + ks*32);
    short8v b1 = *(const short8v*)(Bb + 16*SW + ks*32);
    short8v b2 = *(const short8v*)(Bb + 32*SW + ks*32);
    short8v b3 = *(const short8v*)(Bb + 48*SW + ks*32);
    acc[0][0] = __builtin_amdgcn_mfma_f32_16x16x32_bf16(a0, b0, acc[0][0], 0, 0, 0);
    acc[0][1] = __builtin_amdgcn_mfma_f32_16x16x32_bf16(a0, b1, acc[0][1], 0, 0, 0);
    acc[0][2] = __builtin_amdgcn_mfma_f32_16x16x32_bf16(a0, b2, acc[0][2], 0, 0, 0);
    acc[0][3] = __builtin_amdgcn_mfma_f32_16x16x32_bf16(a0, b3, acc[0][3], 0, 0, 0);
    acc[1][0] = __builtin_amdgcn_mfma_f32_16x16x32_bf16(a1, b0, acc[1][0], 0, 0, 0);
    acc[1][1] = __builtin_amdgcn_mfma_f32_16x16x32_bf16(a1, b1, acc[1][1], 0, 0, 0);
    acc[1][2] = __builtin_amdgcn_mfma_f32_16x16x32_bf16(a1, b2, acc[1][2], 0, 0, 0);
    acc[1][3] = __builtin_amdgcn_mfma_f32_16x16x32_bf16(a1, b3, acc[1][3], 0, 0, 0);
  }

  float* Pk = P + (size_t)blockIdx.z * rows * ldp;
  #pragma unroll
  for (int rf=0;rf<2;rf++){
    int rbase = r0 + 32*w + 16*rf + 4*(l >> 4);
    #pragma unroll
    for (int cf=0;cf<4;cf++){
      int c = c0 + 16*cf + (l & 15);
      if (c >= NC) continue;
      #pragma unroll
      for (int r=0;r<4;r++){
        int rr = rbase + r;
        if (rr < rows) Pk[(size_t)rr*ldp + c] = acc[rf][cf][r];
      }
    }
  }
}

// sum nk partials + bias (+relu) -> f32 out
__global__ __launch_bounds__(256) void k_reduce(
    const float* __restrict__ P, int nk, int rows, int NC,
    const float* __restrict__ bias, float* __restrict__ out, int relu)
{
  int i = blockIdx.x*blockDim.x + threadIdx.x;
  int tot = rows*(NC/4);
  if (i >= tot) return;
  int r = i / (NC/4), c4 = i % (NC/4);
  float4 acc = *(const float4*)&bias[4*c4];
  for (int kc = 0; kc < nk; ++kc){
    float4 p = *(const float4*)&P[((size_t)kc*rows + r)*NC + 4*c4];
    acc.x += p.x; acc.y += p.y; acc.z += p.z; acc.w += p.w;
  }
  if (relu){
    acc.x = fmaxf(acc.x, 0.f); acc.y = fmaxf(acc.y, 0.f);
    acc.z = fmaxf(acc.z, 0.f); acc.w = fmaxf(acc.w, 0.f);
  }
  *(float4*)&out[(size_t)r*NC + 4*c4] = acc;
}

// ---------------- launcher ----------------

extern "C" void kernel_launch(void* const* d_in, const int* in_sizes, int n_in,
                              void* d_out, int out_size, void* d_ws, size_t ws_size,
                              hipStream_t stream)
{
  const float* x   = (const float*)d_in[0];
  const int*   ei  = (const int*)d_in[1];
  const int*   batch = (const int*)d_in[2];
  const float* W1  = (const float*)d_in[3]; const float* b1  = (const float*)d_in[4];
  const float* W2  = (const float*)d_in[5]; const float* b2  = (const float*)d_in[6];
  const float* W3  = (const float*)d_in[7]; const float* b3  = (const float*)d_in[8];
  const float* Wg1 = (const float*)d_in[9]; const float* bg1 = (const float*)d_in[10];
  const float* Wg2 = (const float*)d_in[11]; const float* bg2 = (const float*)d_in[12];
  float* out = (float*)d_out;

  const int F1 = 75;
  int n = in_sizes[0] / F1;          // 100000
  int E = in_sizes[1] / 2;           // 800000
  int G = out_size / 128;            // 512
  const int* row = ei;
  const int* col = ei + E;

  char* ws = (char*)d_ws;
  size_t off = 0;
  auto alloc = [&](size_t bytes){ size_t o = off; off += (bytes + 255) & ~(size_t)255; return o; };
  u16*   xb    = (u16*)  (ws + alloc((size_t)n*80*2));   // padded bf16 x; aliased as h1 later
  u16*   qb    = (u16*)  (ws + alloc((size_t)n*160*2));  // propagated features (stride 80 or 160)
  u16*   h2b   = (u16*)  (ws + alloc((size_t)n*160*2));
  float* dinv  = (float*)(ws + alloc((size_t)n*4));
  int*   indeg = (int*)  (ws + alloc((size_t)n*4));
  int*   rp    = (int*)  (ws + alloc((size_t)(n+1)*4));
  int*   nxt   = (int*)  (ws + alloc((size_t)n*4));
  int*   csr   = (int*)  (ws + alloc((size_t)E*4));
  int*   bsums = (int*)  (ws + alloc(1024*4));
  unsigned* g  = (unsigned*)(ws + alloc((size_t)G*320*4));
  float* gh    = (float*)(ws + alloc((size_t)G*1024*4));
  float* ph1   = (float*)(ws + alloc((size_t)5*G*1024*4));   // head-1 partials
  float* ph2   = (float*)(ws + alloc((size_t)16*G*128*4));   // head-2 partials
  u16* Wt1  = (u16*)(ws + alloc((size_t)128*96*2));
  u16* Wt2  = (u16*)(ws + alloc((size_t)192*96*2));
  u16* Wt3  = (u16*)(ws + alloc((size_t)320*160*2));
  u16* Wg1t = (u16*)(ws + alloc((size_t)1024*320*2));
  u16* Wg2t = (u16*)(ws + alloc((size_t)128*1024*2));
  u16* h1b = xb;   // alias: xb dead after prop1

  hipMemsetAsync(indeg, 0, (size_t)n*4, stream);
  hipMemsetAsync(g, 0, (size_t)G*320*4, stream);

  k_deg<<<(E+255)/256, 256, 0, stream>>>(col, indeg, E);
  k_dinv<<<(n+255)/256, 256, 0, stream>>>(indeg, dinv, n);

  int nb = (n + 1023) / 1024;
  k_scan1<<<nb, 256, 0, stream>>>(indeg, rp, bsums, n);
  k_scan2<<<1, 128, 0, stream>>>(bsums, rp, nb, n);
  k_scan3<<<(n+255)/256, 256, 0, stream>>>(rp, nxt, bsums, n);
  k_scatter<<<(E+255)/256, 256, 0, stream>>>(row, col, nxt, csr, E);

  k_padb<<<4096, 256, 0, stream>>>(x, xb, n);
  k_wt<<<(128*96+255)/256, 256, 0, stream>>>(W1, Wt1, 75, 75, 96, 128);
  k_wt<<<(192*96+255)/256, 256, 0, stream>>>(W2, Wt2, 75, 150, 96, 192);
  k_wt<<<(320*160+255)/256, 256, 0, stream>>>(W3, Wt3, 150, 300, 160, 320);
  k_wt<<<(1024*320+255)/256, 256, 0, stream>>>(Wg1, Wg1t, 300, 1024, 320, 1024);
  k_wt<<<(128*1024+255)/256, 256, 0, stream>>>(Wg2, Wg2t, 1024, 128, 1024, 128);

  int mb64 = (n + 63) / 64;     // 1563

  // layer 1: q = Ahat xb ; h1 = relu(q@W1+b1)
  k_prop_bf<80><<<(n+24)/25, 256, 0, stream>>>(xb, dinv, rp, csr, qb, n);
  k_gemm_bf<96,80,0><<<mb64, 256, 0, stream>>>(qb, Wt1, b1, h1b, 80, 75, 2,
                                               nullptr, nullptr, 0, n, G);
  // layer 2
  k_prop_bf<80><<<(n+24)/25, 256, 0, stream>>>(h1b, dinv, rp, csr, qb, n);
  k_gemm_bf<96,80,0><<<mb64, 256, 0, stream>>>(qb, Wt2, b2, h2b, 160, 150, 3,
                                               nullptr, nullptr, 0, n, G);
  // layer 3 + fused relu + segment-max pool -> g (f32 bits, stride 320)
  k_prop_bf<160><<<(n+11)/12, 256, 0, stream>>>(h2b, dinv, rp, csr, qb, n);
  k_gemm_bf<160,160,1><<<mb64, 256, 0, stream>>>(qb, Wt3, b3, nullptr, 0, 300, 5,
                                                 batch, g, 320, n, G);
  // head 1: gh = relu(g @ Wg1 + bg1)   [K-split: 5 chunks of 64 over K=320]
  {
    dim3 grid((G+127)/128, 1024/64, 5);
    k_gemm_kc<<<grid, 256, 0, stream>>>((const float*)g, 320, Wg1t, 320, ph1, 1024, G, 1024);
    int tot = G*(1024/4);
    k_reduce<<<(tot+255)/256, 256, 0, stream>>>(ph1, 5, G, 1024, bg1, gh, 1);
  }
  // head 2: out = gh @ Wg2 + bg2   [K-split: 16 chunks of 64 over K=1024]
  {
    dim3 grid((G+127)/128, 128/64, 16);
    k_gemm_kc<<<grid, 256, 0, stream>>>(gh, 1024, Wg2t, 1024, ph2, 128, G, 128);
    int tot = G*(128/4);
    k_reduce<<<(tot+255)/256, 256, 0, stream>>>(ph2, 16, G, 128, bg2, out, 0);
  }
}